// Round 1
// baseline (3096.281 us; speedup 1.0000x reference)
//
#include <hip/hip_runtime.h>

constexpr int N_NODES = 50000;
constexpr int N_EDGES = 800000;
constexpr int ND  = 32;
constexpr int ED  = 16;
constexpr int HID = 96;
constexpr int NLAYER = 3;

typedef unsigned short ushort_t;
typedef unsigned int uint_t;
typedef __attribute__((ext_vector_type(8))) short bf16x8;
typedef __attribute__((ext_vector_type(4))) float f32x4;

__device__ __forceinline__ float bf2f(ushort_t u) {
    union { float f; uint_t ui; } c; c.ui = ((uint_t)u) << 16; return c.f;
}
__device__ __forceinline__ ushort_t f2bf(float f) {
    uint_t u = __float_as_uint(f);
    return (ushort_t)((u + 0x7FFFu + ((u >> 16) & 1u)) >> 16);  // RNE
}

// ---------------- CSR build (by dst), once per call ----------------
__global__ void k_rank(const int* __restrict__ dst, int* __restrict__ cnt,
                       int* __restrict__ rank) {
    int e = blockIdx.x * 256 + threadIdx.x;
    if (e >= N_EDGES) return;
    rank[e] = atomicAdd(&cnt[dst[e]], 1);
}

__global__ void k_scan_block(const int* __restrict__ deg, int* __restrict__ rowptr,
                             int* __restrict__ bsum) {
    __shared__ int s[256];
    int i = blockIdx.x * 256 + threadIdx.x;
    int v = (i < N_NODES) ? deg[i] : 0;
    s[threadIdx.x] = v;
    __syncthreads();
    for (int off = 1; off < 256; off <<= 1) {
        int t = (threadIdx.x >= off) ? s[threadIdx.x - off] : 0;
        __syncthreads();
        s[threadIdx.x] += t;
        __syncthreads();
    }
    if (i < N_NODES) rowptr[i] = s[threadIdx.x] - v;
    if (threadIdx.x == 255) bsum[blockIdx.x] = s[255];
}

__global__ void k_scan_bsum(int* __restrict__ bsum, int nb) {
    __shared__ int s[256];
    int t = threadIdx.x;
    int v = (t < nb) ? bsum[t] : 0;
    s[t] = v;
    __syncthreads();
    for (int off = 1; off < 256; off <<= 1) {
        int tv = (t >= off) ? s[t - off] : 0;
        __syncthreads();
        s[t] += tv;
        __syncthreads();
    }
    if (t < nb) bsum[t] = s[t] - v;
}

__global__ void k_scan_add(int* __restrict__ rowptr, const int* __restrict__ bsum) {
    int i = blockIdx.x * 256 + threadIdx.x;
    if (i < N_NODES) rowptr[i] += bsum[blockIdx.x];
    if (i == 0) rowptr[N_NODES] = N_EDGES;
}

__global__ void k_place(const int* __restrict__ src, const int* __restrict__ dst,
                        const int* __restrict__ rank, const int* __restrict__ rowptr,
                        int2* __restrict__ csre) {
    int e = blockIdx.x * 256 + threadIdx.x;
    if (e >= N_EDGES) return;
    int p = rowptr[dst[e]] + rank[e];
    csre[p] = make_int2(src[e], e);
}

__global__ void k_gather(const int2* __restrict__ csre, const int* __restrict__ dstA,
                         const float* __restrict__ eattr, int* __restrict__ srcs,
                         int* __restrict__ pdst, ushort_t* __restrict__ ea) {
    int p = blockIdx.x * 256 + threadIdx.x;
    if (p >= N_EDGES) return;
    int2 se = csre[p];
    int e = se.y;
    srcs[p] = se.x;
    pdst[p] = dstA[e];
    const float4* er = (const float4*)(eattr + (size_t)e * ED);
    float4 v0 = er[0], v1 = er[1], v2 = er[2], v3 = er[3];
    uint4 w0, w1;
    w0.x = (uint_t)f2bf(v0.x) | ((uint_t)f2bf(v0.y) << 16);
    w0.y = (uint_t)f2bf(v0.z) | ((uint_t)f2bf(v0.w) << 16);
    w0.z = (uint_t)f2bf(v1.x) | ((uint_t)f2bf(v1.y) << 16);
    w0.w = (uint_t)f2bf(v1.z) | ((uint_t)f2bf(v1.w) << 16);
    w1.x = (uint_t)f2bf(v2.x) | ((uint_t)f2bf(v2.y) << 16);
    w1.y = (uint_t)f2bf(v2.z) | ((uint_t)f2bf(v2.w) << 16);
    w1.z = (uint_t)f2bf(v3.x) | ((uint_t)f2bf(v3.y) << 16);
    w1.w = (uint_t)f2bf(v3.z) | ((uint_t)f2bf(v3.w) << 16);
    uint4* ew = (uint4*)(ea + (size_t)p * ED);
    ew[0] = w0;
    ew[1] = w1;
}

// ---------------- proj: h = x @ proj_w + proj_b  (K=32) ----------------
__global__ __launch_bounds__(192) void k_proj(const float* __restrict__ x,
                                              const float* __restrict__ pw,
                                              const float* __restrict__ pb,
                                              float* __restrict__ h) {
    int t = threadIdx.x;
    int c = t % 96, half = t / 96;
    float wreg[ND];
#pragma unroll
    for (int k = 0; k < ND; k++) wreg[k] = pw[k * HID + c];
    float b = pb[c];
    int n0 = blockIdx.x * 16 + half * 8;
    for (int i = 0; i < 8; i += 2) {
        int na = n0 + i, nb = na + 1;
        const float4* xa = (const float4*)(x + (size_t)na * ND);
        const float4* xb = (const float4*)(x + (size_t)nb * ND);
        float accA = b, accB = b;
#pragma unroll
        for (int k4 = 0; k4 < ND / 4; k4++) {
            float4 va = xa[k4], vb = xb[k4];
            accA += va.x * wreg[4 * k4] + va.y * wreg[4 * k4 + 1] +
                    va.z * wreg[4 * k4 + 2] + va.w * wreg[4 * k4 + 3];
            accB += vb.x * wreg[4 * k4] + vb.y * wreg[4 * k4 + 1] +
                    vb.z * wreg[4 * k4 + 2] + vb.w * wreg[4 * k4 + 3];
        }
        h[(size_t)na * HID + c] = accA;
        h[(size_t)nb * HID + c] = accB;
    }
}

// ---- k_linlr_mfma: [xl|xr] = h @ [Wl|Wr] + [bl|br], bf16 out, MFMA ----
__global__ __launch_bounds__(256) void k_linlr_mfma(
    const float* __restrict__ h, const float* __restrict__ Wl,
    const float* __restrict__ bl, const float* __restrict__ Wr,
    const float* __restrict__ br, ushort_t* __restrict__ xl,
    ushort_t* __restrict__ xr) {
    __shared__ ushort_t sW[192 * 104];
    __shared__ float sB[192];
    int t = threadIdx.x;

    for (int idx = t; idx < 192 * 96; idx += 256) {
        int n = idx % 192, k = idx / 192;
        float v = (n < 96) ? Wl[k * 96 + n] : Wr[k * 96 + (n - 96)];
        sW[n * 104 + k] = f2bf(v);
    }
    if (t < 192) sB[t] = (t < 96) ? bl[t] : br[t - 96];
    __syncthreads();

    int wv = t >> 6, lane = t & 63;
    int m0 = blockIdx.x * 64 + wv * 16;
    if (m0 >= N_NODES) return;
    int m = lane & 15, quad = lane >> 4;

    bf16x8 afr[3];
    const float* hrow = h + (size_t)(m0 + m) * HID;
#pragma unroll
    for (int s = 0; s < 3; s++) {
        float4 v0 = *(const float4*)(hrow + s * 32 + quad * 8);
        float4 v1 = *(const float4*)(hrow + s * 32 + quad * 8 + 4);
        bf16x8 a;
        a[0] = (short)f2bf(v0.x); a[1] = (short)f2bf(v0.y);
        a[2] = (short)f2bf(v0.z); a[3] = (short)f2bf(v0.w);
        a[4] = (short)f2bf(v1.x); a[5] = (short)f2bf(v1.y);
        a[6] = (short)f2bf(v1.z); a[7] = (short)f2bf(v1.w);
        afr[s] = a;
    }

#pragma unroll
    for (int nt = 0; nt < 12; nt++) {
        int ch = nt * 16 + m;
        f32x4 acc = {0.f, 0.f, 0.f, 0.f};
#pragma unroll
        for (int s = 0; s < 3; s++) {
            bf16x8 bfr = *(const bf16x8*)(sW + (nt * 16 + m) * 104 + s * 32 + quad * 8);
            acc = __builtin_amdgcn_mfma_f32_16x16x32_bf16(afr[s], bfr, acc, 0, 0, 0);
        }
        float bias = sB[ch];
        ushort_t* dst = (ch < 96) ? (xl + (size_t)(m0 + quad * 4) * HID + ch)
                                  : (xr + (size_t)(m0 + quad * 4) * HID + (ch - 96));
#pragma unroll
        for (int r = 0; r < 4; r++)
            dst[(size_t)r * HID] = f2bf(acc[r] + bias);
    }
}

// ---- k_evagg: FUSED attention-weight + aggregation.
// Lane (col,quad) owns 8 CONSECUTIVE CSR positions p0 = wid*128 + col*8
// (edge identity in the MFMA is just "whatever B-column col carries", so
// any batch->edge bijection is valid). CSR is dst-sorted, so each lane's
// serial strip has ~1.5 distinct dst values:
//  * Sum(ev*xl) accumulates in 24 registers, flushed by atomicAdd on
//    dst-change (~15M atomics total -> streaming-rate, low contention).
//  * xr[dst] row is register-reused across batches when dst unchanged
//    (cuts xr gather issue ~5x vs reloading every batch).
// This deletes k_agg's second 153MB/layer random-gather pass and the
// 25MB/layer evf round-trip. __launch_bounds__(256,3): cap 170 VGPR,
// 3 waves/SIMD.
__global__ __launch_bounds__(256, 3) void k_evagg(
    const ushort_t* __restrict__ xlb, const ushort_t* __restrict__ xrb,
    const ushort_t* __restrict__ ea, const int* __restrict__ srcs,
    const int* __restrict__ pdst, const float* __restrict__ WeL,
    const float* __restrict__ attL, float* __restrict__ accsum,
    float* __restrict__ accden) {
    int wid = blockIdx.x * 4 + (threadIdx.x >> 6);
    int lane = threadIdx.x & 63;
    if (wid >= N_EDGES / 128) return;
    int col = lane & 15, quad = lane >> 4;

    // wave-invariant A fragments (We^T, remapped channels):
    // lane (quad,col) D rows cover channels quad*24 + mc*4 + r, head == quad.
    bf16x8 afr[6];
#pragma unroll
    for (int mc = 0; mc < 6; mc++) {
        bf16x8 a = {0, 0, 0, 0, 0, 0, 0, 0};
        if (quad < 2) {
            int ch = (col >> 2) * 24 + mc * 4 + (col & 3);
#pragma unroll
            for (int j = 0; j < 8; j++)
                a[j] = (short)f2bf(WeL[(quad * 8 + j) * HID + ch]);
        }
        afr[mc] = a;
    }
    float attr[6][4];
#pragma unroll
    for (int mc = 0; mc < 6; mc++)
#pragma unroll
        for (int r = 0; r < 4; r++)
            attr[mc][r] = attL[quad * 24 + mc * 4 + r];

    // per-lane stream: 8 consecutive CSR edges (no shuffles on the
    // address path -> loads issue immediately)
    int p0 = wid * 128 + col * 8;
    int4 s0  = *(const int4*)(srcs + p0);
    int4 s1  = *(const int4*)(srcs + p0 + 4);
    int4 dd0 = *(const int4*)(pdst + p0);
    int4 dd1 = *(const int4*)(pdst + p0 + 4);
    int msrc[8] = {s0.x, s0.y, s0.z, s0.w, s1.x, s1.y, s1.z, s1.w};
    int mdst[8] = {dd0.x, dd0.y, dd0.z, dd0.w, dd1.x, dd1.y, dd1.z, dd1.w};

    bf16x8 bfr[2];
    uint4 xq[2][3], rq[2][3];

    // invariant: after issue(b,s), rq[s] holds xr row of mdst[b]
    auto issue = [&](int b, int s) {
        int p = p0 + b;
        bf16x8 z8 = {0, 0, 0, 0, 0, 0, 0, 0};
        bfr[s] = (quad < 2) ? *(const bf16x8*)(ea + (size_t)p * ED + quad * 8) : z8;
        const uint4* xp = (const uint4*)(xlb + (size_t)msrc[b] * HID + quad * 24);
#pragma unroll
        for (int i = 0; i < 3; i++) xq[s][i] = xp[i];
        if (b == 0 || mdst[b] != mdst[b - 1]) {
            const uint4* rp = (const uint4*)(xrb + (size_t)mdst[b] * HID + quad * 24);
#pragma unroll
            for (int i = 0; i < 3; i++) rq[s][i] = rp[i];
        } else {
#pragma unroll
            for (int i = 0; i < 3; i++) rq[s][i] = rq[s ^ 1][i];
        }
    };

    float acc[24];
#pragma unroll
    for (int j = 0; j < 24; j++) acc[j] = 0.f;
    float accd = 0.f;

    issue(0, 0);
#pragma unroll
    for (int b = 0; b < 8; b++) {
        int pp = b & 1;
        if (b < 7) issue(b + 1, pp ^ 1);

        f32x4 zero4 = {0.f, 0.f, 0.f, 0.f};
        f32x4 d[6];
#pragma unroll
        for (int mc = 0; mc < 6; mc++)
            d[mc] = __builtin_amdgcn_mfma_f32_16x16x32_bf16(afr[mc], bfr[pp], zero4, 0, 0, 0);

        uint_t ux[12] = {xq[pp][0].x, xq[pp][0].y, xq[pp][0].z, xq[pp][0].w,
                         xq[pp][1].x, xq[pp][1].y, xq[pp][1].z, xq[pp][1].w,
                         xq[pp][2].x, xq[pp][2].y, xq[pp][2].z, xq[pp][2].w};
        uint_t ur[12] = {rq[pp][0].x, rq[pp][0].y, rq[pp][0].z, rq[pp][0].w,
                         rq[pp][1].x, rq[pp][1].y, rq[pp][1].z, rq[pp][1].w,
                         rq[pp][2].x, rq[pp][2].y, rq[pp][2].z, rq[pp][2].w};
        float logit = 0.f;
#pragma unroll
        for (int mc = 0; mc < 6; mc++) {
            uint_t aL = ux[2 * mc], aH = ux[2 * mc + 1];
            uint_t rL = ur[2 * mc], rH = ur[2 * mc + 1];
            float x0 = bf2f((ushort_t)(aL & 0xffff)), x1 = bf2f((ushort_t)(aL >> 16));
            float x2 = bf2f((ushort_t)(aH & 0xffff)), x3 = bf2f((ushort_t)(aH >> 16));
            float r0 = bf2f((ushort_t)(rL & 0xffff)), r1 = bf2f((ushort_t)(rL >> 16));
            float r2 = bf2f((ushort_t)(rH & 0xffff)), r3 = bf2f((ushort_t)(rH >> 16));
            float z0 = x0 + r0 + d[mc][0]; z0 = z0 > 0.f ? z0 : 0.2f * z0;
            float z1 = x1 + r1 + d[mc][1]; z1 = z1 > 0.f ? z1 : 0.2f * z1;
            float z2 = x2 + r2 + d[mc][2]; z2 = z2 > 0.f ? z2 : 0.2f * z2;
            float z3 = x3 + r3 + d[mc][3]; z3 = z3 > 0.f ? z3 : 0.2f * z3;
            logit += z0 * attr[mc][0] + z1 * attr[mc][1] +
                     z2 * attr[mc][2] + z3 * attr[mc][3];
        }
        float ev = __expf(logit);

        // aggregate in registers: xl values are already resident (xq[pp]);
        // re-unpack (cheap shifts) instead of keeping 24 extra floats live.
#pragma unroll
        for (int mc = 0; mc < 6; mc++) {
            uint_t aL = ux[2 * mc], aH = ux[2 * mc + 1];
            acc[4 * mc + 0] += ev * bf2f((ushort_t)(aL & 0xffff));
            acc[4 * mc + 1] += ev * bf2f((ushort_t)(aL >> 16));
            acc[4 * mc + 2] += ev * bf2f((ushort_t)(aH & 0xffff));
            acc[4 * mc + 3] += ev * bf2f((ushort_t)(aH >> 16));
        }
        accd += ev;

        // flush on dst-change or stream end (~1.5 flushes per lane)
        if ((b == 7) || (mdst[b + 1] != mdst[b])) {
            float* ap = accsum + (size_t)mdst[b] * HID + quad * 24;
#pragma unroll
            for (int j = 0; j < 24; j++) atomicAdd(ap + j, acc[j]);
            atomicAdd(accden + 4 * mdst[b] + quad, accd);
            if (b < 7) {
#pragma unroll
                for (int j = 0; j < 24; j++) acc[j] = 0.f;
                accd = 0.f;
            }
        }
    }
}

// ---- k_lnfin: h = LN(h + acc/den + conv_b). Pure streaming, 8 nodes/wave,
// 8 lanes x 12ch per node; cross-channel reduce = shfl_xor 1,2,4. ----
__global__ __launch_bounds__(256) void k_lnfin(
    const float* __restrict__ acc, const float* __restrict__ den,
    const float* __restrict__ convb, const float* __restrict__ lng,
    const float* __restrict__ lnb, float* __restrict__ h) {
    int lane = threadIdx.x & 63;
    int slot = lane >> 3, q = lane & 7;
    int node = blockIdx.x * 32 + (threadIdx.x >> 6) * 8 + slot;
    if (node >= N_NODES) return;
    int c0 = q * 12;
    float inv = 1.f / (den[node * 4 + (q >> 1)] + 1e-16f);
    size_t nb = (size_t)node * HID + c0;
    float4 a0 = *(const float4*)(acc + nb);
    float4 a1 = *(const float4*)(acc + nb + 4);
    float4 a2 = *(const float4*)(acc + nb + 8);
    float4 h0 = *(const float4*)(h + nb);
    float4 h1 = *(const float4*)(h + nb + 4);
    float4 h2 = *(const float4*)(h + nb + 8);
    float4 c0v = *(const float4*)(convb + c0);
    float4 c1v = *(const float4*)(convb + c0 + 4);
    float4 c2v = *(const float4*)(convb + c0 + 8);
    float vv[12] = {
        h0.x + a0.x * inv + c0v.x, h0.y + a0.y * inv + c0v.y,
        h0.z + a0.z * inv + c0v.z, h0.w + a0.w * inv + c0v.w,
        h1.x + a1.x * inv + c1v.x, h1.y + a1.y * inv + c1v.y,
        h1.z + a1.z * inv + c1v.z, h1.w + a1.w * inv + c1v.w,
        h2.x + a2.x * inv + c2v.x, h2.y + a2.y * inv + c2v.y,
        h2.z + a2.z * inv + c2v.z, h2.w + a2.w * inv + c2v.w};
    float sm = 0.f;
#pragma unroll
    for (int j = 0; j < 12; j++) sm += vv[j];
    sm += __shfl_xor(sm, 1); sm += __shfl_xor(sm, 2); sm += __shfl_xor(sm, 4);
    float mu = sm * (1.f / 96.f);
    float sv = 0.f;
#pragma unroll
    for (int j = 0; j < 12; j++) {
        vv[j] -= mu;
        sv += vv[j] * vv[j];
    }
    sv += __shfl_xor(sv, 1); sv += __shfl_xor(sv, 2); sv += __shfl_xor(sv, 4);
    float rstd = rsqrtf(sv * (1.f / 96.f) + 1e-5f);
    float4 g0 = *(const float4*)(lng + c0);
    float4 g1 = *(const float4*)(lng + c0 + 4);
    float4 g2 = *(const float4*)(lng + c0 + 8);
    float4 b0 = *(const float4*)(lnb + c0);
    float4 b1 = *(const float4*)(lnb + c0 + 4);
    float4 b2 = *(const float4*)(lnb + c0 + 8);
    *(float4*)(h + nb) = make_float4(
        vv[0] * rstd * g0.x + b0.x, vv[1] * rstd * g0.y + b0.y,
        vv[2] * rstd * g0.z + b0.z, vv[3] * rstd * g0.w + b0.w);
    *(float4*)(h + nb + 4) = make_float4(
        vv[4] * rstd * g1.x + b1.x, vv[5] * rstd * g1.y + b1.y,
        vv[6] * rstd * g1.z + b1.z, vv[7] * rstd * g1.w + b1.w);
    *(float4*)(h + nb + 8) = make_float4(
        vv[8] * rstd * g2.x + b2.x, vv[9] * rstd * g2.y + b2.y,
        vv[10] * rstd * g2.z + b2.z, vv[11] * rstd * g2.w + b2.w);
}

// ---- k_head_mfma: out = gelu(h@W1+b1)@W2+b2 via MFMA ----
__global__ __launch_bounds__(256) void k_head_mfma(
    const float* __restrict__ h, const float* __restrict__ W1,
    const float* __restrict__ b1, const float* __restrict__ W2,
    const float* __restrict__ b2, float* __restrict__ out) {
    __shared__ ushort_t sW[48 * 104];
    __shared__ float sB1[48];
    __shared__ float sW2[48];
    int t = threadIdx.x;
    for (int idx = t; idx < 48 * 96; idx += 256) {
        int j = idx % 48, k = idx / 48;
        sW[j * 104 + k] = f2bf(W1[k * 48 + j]);
    }
    if (t < 48) { sB1[t] = b1[t]; sW2[t] = W2[t]; }
    __syncthreads();

    int wv = t >> 6, lane = t & 63;
    int m0 = blockIdx.x * 64 + wv * 16;
    if (m0 >= N_NODES) return;
    int col = lane & 15, quad = lane >> 4;

    bf16x8 afr[3];
    const float* hrow = h + (size_t)(m0 + col) * HID;
#pragma unroll
    for (int s = 0; s < 3; s++) {
        float4 v0 = *(const float4*)(hrow + s * 32 + quad * 8);
        float4 v1 = *(const float4*)(hrow + s * 32 + quad * 8 + 4);
        bf16x8 a;
        a[0] = (short)f2bf(v0.x); a[1] = (short)f2bf(v0.y);
        a[2] = (short)f2bf(v0.z); a[3] = (short)f2bf(v0.w);
        a[4] = (short)f2bf(v1.x); a[5] = (short)f2bf(v1.y);
        a[6] = (short)f2bf(v1.z); a[7] = (short)f2bf(v1.w);
        afr[s] = a;
    }

    const float inv_sqrt2 = 0.70710678118654752f;
    float y0 = 0.f, y1 = 0.f, y2 = 0.f, y3 = 0.f;
#pragma unroll
    for (int nt = 0; nt < 3; nt++) {
        f32x4 acc = {0.f, 0.f, 0.f, 0.f};
#pragma unroll
        for (int s = 0; s < 3; s++) {
            bf16x8 bfr = *(const bf16x8*)(sW + (nt * 16 + col) * 104 + s * 32 + quad * 8);
            acc = __builtin_amdgcn_mfma_f32_16x16x32_bf16(afr[s], bfr, acc, 0, 0, 0);
        }
        int ch = nt * 16 + col;
        float bias = sB1[ch], w2 = sW2[ch];
        float v, g;
        v = acc[0] + bias; g = 0.5f * v * (1.f + erff(v * inv_sqrt2)); y0 += g * w2;
        v = acc[1] + bias; g = 0.5f * v * (1.f + erff(v * inv_sqrt2)); y1 += g * w2;
        v = acc[2] + bias; g = 0.5f * v * (1.f + erff(v * inv_sqrt2)); y2 += g * w2;
        v = acc[3] + bias; g = 0.5f * v * (1.f + erff(v * inv_sqrt2)); y3 += g * w2;
    }
    y0 += __shfl_xor(y0, 1); y0 += __shfl_xor(y0, 2);
    y0 += __shfl_xor(y0, 4); y0 += __shfl_xor(y0, 8);
    y1 += __shfl_xor(y1, 1); y1 += __shfl_xor(y1, 2);
    y1 += __shfl_xor(y1, 4); y1 += __shfl_xor(y1, 8);
    y2 += __shfl_xor(y2, 1); y2 += __shfl_xor(y2, 2);
    y2 += __shfl_xor(y2, 4); y2 += __shfl_xor(y2, 8);
    y3 += __shfl_xor(y3, 1); y3 += __shfl_xor(y3, 2);
    y3 += __shfl_xor(y3, 4); y3 += __shfl_xor(y3, 8);
    if (col == 0) {
        float bb = b2[0];
        out[m0 + quad * 4 + 0] = y0 + bb;
        out[m0 + quad * 4 + 1] = y1 + bb;
        out[m0 + quad * 4 + 2] = y2 + bb;
        out[m0 + quad * 4 + 3] = y3 + bb;
    }
}

extern "C" void kernel_launch(void* const* d_in, const int* in_sizes, int n_in,
                              void* d_out, int out_size, void* d_ws, size_t ws_size,
                              hipStream_t stream) {
    const float* x       = (const float*)d_in[0];
    const int*   eidx    = (const int*)  d_in[1];
    const float* eattr   = (const float*)d_in[2];
    const float* proj_w  = (const float*)d_in[3];
    const float* proj_b  = (const float*)d_in[4];
    const float* lin_l_w = (const float*)d_in[5];
    const float* lin_l_b = (const float*)d_in[6];
    const float* lin_r_w = (const float*)d_in[7];
    const float* lin_r_b = (const float*)d_in[8];
    const float* lin_e_w = (const float*)d_in[9];
    const float* att     = (const float*)d_in[10];
    const float* conv_b  = (const float*)d_in[11];
    const float* ln_g    = (const float*)d_in[12];
    const float* ln_b    = (const float*)d_in[13];
    const float* head_w1 = (const float*)d_in[14];
    const float* head_b1 = (const float*)d_in[15];
    const float* head_w2 = (const float*)d_in[16];
    const float* head_b2 = (const float*)d_in[17];
    float* out = (float*)d_out;

    char* p = (char*)d_ws;
    auto alloc = [&](size_t bytes) -> char* {
        char* r = p;
        p += (bytes + 255) & ~size_t(255);
        return r;
    };
    float*    h      = (float*)alloc(sizeof(float) * (size_t)N_NODES * HID);
    ushort_t* xl     = (ushort_t*)alloc(2 * (size_t)N_NODES * HID);
    ushort_t* xr     = (ushort_t*)alloc(2 * (size_t)N_NODES * HID);
    int*      srcs   = (int*)alloc(4 * ((size_t)N_EDGES + 256));
    int*      pdst   = (int*)alloc(4 * ((size_t)N_EDGES + 256));
    ushort_t* ea_csr = (ushort_t*)alloc(2 * (size_t)N_EDGES * ED);
    int*      rowptr = (int*)alloc(4 * (size_t)(N_NODES + 1));
    int*      bsum   = (int*)alloc(4 * 256);

    // union region: CSR-build scratch (9.8MB, used before layers) overlays
    // the layer-phase accumulators (20MB) -> total footprint <= old version.
    char* ubase = alloc(20000000);
    float* accsum = (float*)ubase;                     // 50000*96*4 = 19,200,000 B
    float* accden = (float*)(ubase + 19200000);        //  50000*4*4 =    800,000 B
    int*   cnt    = (int*)ubase;                       //    200,000 B
    int*   rank   = (int*)(ubase + 200192);            //  3,200,000 B
    int2*  csre   = (int2*)(ubase + 200192 + 3200000); //  6,400,000 B (end 9.8MB)

    const int* srcA = eidx;
    const int* dstA = eidx + N_EDGES;

    int ebl = (N_EDGES + 255) / 256;   // 3125
    int nbl = (N_NODES + 255) / 256;   // 196

    hipMemsetAsync(cnt, 0, 4 * (size_t)N_NODES, stream);
    k_rank<<<ebl, 256, 0, stream>>>(dstA, cnt, rank);
    k_scan_block<<<nbl, 256, 0, stream>>>(cnt, rowptr, bsum);
    k_scan_bsum<<<1, 256, 0, stream>>>(bsum, nbl);
    k_scan_add<<<nbl, 256, 0, stream>>>(rowptr, bsum);
    k_place<<<ebl, 256, 0, stream>>>(srcA, dstA, rank, rowptr, csre);
    k_gather<<<ebl, 256, 0, stream>>>(csre, dstA, eattr, srcs, pdst, ea_csr);

    k_proj<<<N_NODES / 16, 192, 0, stream>>>(x, proj_w, proj_b, h);
    for (int l = 0; l < NLAYER; l++) {
        k_linlr_mfma<<<(N_NODES + 63) / 64, 256, 0, stream>>>(
            h, lin_l_w + (size_t)l * HID * HID, lin_l_b + (size_t)l * HID,
            lin_r_w + (size_t)l * HID * HID, lin_r_b + (size_t)l * HID, xl, xr);
        hipMemsetAsync(accsum, 0, 20000000, stream);
        k_evagg<<<1563, 256, 0, stream>>>(xl, xr, ea_csr, srcs, pdst,
                                          lin_e_w + (size_t)l * ED * HID,
                                          att + (size_t)l * HID, accsum, accden);
        k_lnfin<<<(N_NODES + 31) / 32, 256, 0, stream>>>(
            accsum, accden, conv_b + (size_t)l * HID,
            ln_g + (size_t)l * HID, ln_b + (size_t)l * HID, h);
    }
    k_head_mfma<<<(N_NODES + 63) / 64, 256, 0, stream>>>(h, head_w1, head_b1,
                                                         head_w2, head_b2, out);
}

// Round 2
// 533.571 us; speedup vs baseline: 5.8029x; 5.8029x over previous
//
#include <hip/hip_runtime.h>

constexpr int N_NODES = 50000;
constexpr int N_EDGES = 800000;
constexpr int ND  = 32;
constexpr int ED  = 16;
constexpr int HID = 96;
constexpr int NLAYER = 3;

typedef unsigned short ushort_t;
typedef unsigned int uint_t;
typedef __attribute__((ext_vector_type(8))) short bf16x8;
typedef __attribute__((ext_vector_type(4))) float f32x4;

__device__ __forceinline__ float bf2f(ushort_t u) {
    union { float f; uint_t ui; } c; c.ui = ((uint_t)u) << 16; return c.f;
}
__device__ __forceinline__ ushort_t f2bf(float f) {
    uint_t u = __float_as_uint(f);
    return (ushort_t)((u + 0x7FFFu + ((u >> 16) & 1u)) >> 16);  // RNE
}

// ---------------- CSR build (by dst), once per call ----------------
__global__ void k_rank(const int* __restrict__ dst, int* __restrict__ cnt,
                       int* __restrict__ rank) {
    int e = blockIdx.x * 256 + threadIdx.x;
    if (e >= N_EDGES) return;
    rank[e] = atomicAdd(&cnt[dst[e]], 1);
}

__global__ void k_scan_block(const int* __restrict__ deg, int* __restrict__ rowptr,
                             int* __restrict__ bsum) {
    __shared__ int s[256];
    int i = blockIdx.x * 256 + threadIdx.x;
    int v = (i < N_NODES) ? deg[i] : 0;
    s[threadIdx.x] = v;
    __syncthreads();
    for (int off = 1; off < 256; off <<= 1) {
        int t = (threadIdx.x >= off) ? s[threadIdx.x - off] : 0;
        __syncthreads();
        s[threadIdx.x] += t;
        __syncthreads();
    }
    if (i < N_NODES) rowptr[i] = s[threadIdx.x] - v;
    if (threadIdx.x == 255) bsum[blockIdx.x] = s[255];
}

__global__ void k_scan_bsum(int* __restrict__ bsum, int nb) {
    __shared__ int s[256];
    int t = threadIdx.x;
    int v = (t < nb) ? bsum[t] : 0;
    s[t] = v;
    __syncthreads();
    for (int off = 1; off < 256; off <<= 1) {
        int tv = (t >= off) ? s[t - off] : 0;
        __syncthreads();
        s[t] += tv;
        __syncthreads();
    }
    if (t < nb) bsum[t] = s[t] - v;
}

__global__ void k_scan_add(int* __restrict__ rowptr, const int* __restrict__ bsum) {
    int i = blockIdx.x * 256 + threadIdx.x;
    if (i < N_NODES) rowptr[i] += bsum[blockIdx.x];
    if (i == 0) rowptr[N_NODES] = N_EDGES;
}

__global__ void k_place(const int* __restrict__ src, const int* __restrict__ dst,
                        const int* __restrict__ rank, const int* __restrict__ rowptr,
                        int2* __restrict__ csre) {
    int e = blockIdx.x * 256 + threadIdx.x;
    if (e >= N_EDGES) return;
    int p = rowptr[dst[e]] + rank[e];
    csre[p] = make_int2(src[e], e);
}

__global__ void k_gather(const int2* __restrict__ csre, const int* __restrict__ dstA,
                         const float* __restrict__ eattr, int* __restrict__ srcs,
                         int* __restrict__ pdst, ushort_t* __restrict__ ea) {
    int p = blockIdx.x * 256 + threadIdx.x;
    if (p >= N_EDGES) return;
    int2 se = csre[p];
    int e = se.y;
    srcs[p] = se.x;
    pdst[p] = dstA[e];
    const float4* er = (const float4*)(eattr + (size_t)e * ED);
    float4 v0 = er[0], v1 = er[1], v2 = er[2], v3 = er[3];
    uint4 w0, w1;
    w0.x = (uint_t)f2bf(v0.x) | ((uint_t)f2bf(v0.y) << 16);
    w0.y = (uint_t)f2bf(v0.z) | ((uint_t)f2bf(v0.w) << 16);
    w0.z = (uint_t)f2bf(v1.x) | ((uint_t)f2bf(v1.y) << 16);
    w0.w = (uint_t)f2bf(v1.z) | ((uint_t)f2bf(v1.w) << 16);
    w1.x = (uint_t)f2bf(v2.x) | ((uint_t)f2bf(v2.y) << 16);
    w1.y = (uint_t)f2bf(v2.z) | ((uint_t)f2bf(v2.w) << 16);
    w1.z = (uint_t)f2bf(v3.x) | ((uint_t)f2bf(v3.y) << 16);
    w1.w = (uint_t)f2bf(v3.z) | ((uint_t)f2bf(v3.w) << 16);
    uint4* ew = (uint4*)(ea + (size_t)p * ED);
    ew[0] = w0;
    ew[1] = w1;
}

// ---------------- proj: h = x @ proj_w + proj_b  (K=32) ----------------
__global__ __launch_bounds__(192) void k_proj(const float* __restrict__ x,
                                              const float* __restrict__ pw,
                                              const float* __restrict__ pb,
                                              float* __restrict__ h) {
    int t = threadIdx.x;
    int c = t % 96, half = t / 96;
    float wreg[ND];
#pragma unroll
    for (int k = 0; k < ND; k++) wreg[k] = pw[k * HID + c];
    float b = pb[c];
    int n0 = blockIdx.x * 16 + half * 8;
    for (int i = 0; i < 8; i += 2) {
        int na = n0 + i, nb = na + 1;
        const float4* xa = (const float4*)(x + (size_t)na * ND);
        const float4* xb = (const float4*)(x + (size_t)nb * ND);
        float accA = b, accB = b;
#pragma unroll
        for (int k4 = 0; k4 < ND / 4; k4++) {
            float4 va = xa[k4], vb = xb[k4];
            accA += va.x * wreg[4 * k4] + va.y * wreg[4 * k4 + 1] +
                    va.z * wreg[4 * k4 + 2] + va.w * wreg[4 * k4 + 3];
            accB += vb.x * wreg[4 * k4] + vb.y * wreg[4 * k4 + 1] +
                    vb.z * wreg[4 * k4 + 2] + vb.w * wreg[4 * k4 + 3];
        }
        h[(size_t)na * HID + c] = accA;
        h[(size_t)nb * HID + c] = accB;
    }
}

// ---- k_linlr_mfma: [xl|xr] = h @ [Wl|Wr] + [bl|br], bf16 out, MFMA ----
__global__ __launch_bounds__(256) void k_linlr_mfma(
    const float* __restrict__ h, const float* __restrict__ Wl,
    const float* __restrict__ bl, const float* __restrict__ Wr,
    const float* __restrict__ br, ushort_t* __restrict__ xl,
    ushort_t* __restrict__ xr) {
    __shared__ ushort_t sW[192 * 104];
    __shared__ float sB[192];
    int t = threadIdx.x;

    for (int idx = t; idx < 192 * 96; idx += 256) {
        int n = idx % 192, k = idx / 192;
        float v = (n < 96) ? Wl[k * 96 + n] : Wr[k * 96 + (n - 96)];
        sW[n * 104 + k] = f2bf(v);
    }
    if (t < 192) sB[t] = (t < 96) ? bl[t] : br[t - 96];
    __syncthreads();

    int wv = t >> 6, lane = t & 63;
    int m0 = blockIdx.x * 64 + wv * 16;
    if (m0 >= N_NODES) return;
    int m = lane & 15, quad = lane >> 4;

    bf16x8 afr[3];
    const float* hrow = h + (size_t)(m0 + m) * HID;
#pragma unroll
    for (int s = 0; s < 3; s++) {
        float4 v0 = *(const float4*)(hrow + s * 32 + quad * 8);
        float4 v1 = *(const float4*)(hrow + s * 32 + quad * 8 + 4);
        bf16x8 a;
        a[0] = (short)f2bf(v0.x); a[1] = (short)f2bf(v0.y);
        a[2] = (short)f2bf(v0.z); a[3] = (short)f2bf(v0.w);
        a[4] = (short)f2bf(v1.x); a[5] = (short)f2bf(v1.y);
        a[6] = (short)f2bf(v1.z); a[7] = (short)f2bf(v1.w);
        afr[s] = a;
    }

#pragma unroll
    for (int nt = 0; nt < 12; nt++) {
        int ch = nt * 16 + m;
        f32x4 acc = {0.f, 0.f, 0.f, 0.f};
#pragma unroll
        for (int s = 0; s < 3; s++) {
            bf16x8 bfr = *(const bf16x8*)(sW + (nt * 16 + m) * 104 + s * 32 + quad * 8);
            acc = __builtin_amdgcn_mfma_f32_16x16x32_bf16(afr[s], bfr, acc, 0, 0, 0);
        }
        float bias = sB[ch];
        ushort_t* dst = (ch < 96) ? (xl + (size_t)(m0 + quad * 4) * HID + ch)
                                  : (xr + (size_t)(m0 + quad * 4) * HID + (ch - 96));
#pragma unroll
        for (int r = 0; r < 4; r++)
            dst[(size_t)r * HID] = f2bf(acc[r] + bias);
    }
}

// ---- k_ev: edge-parallel attention weights via MFMA, CSR order.
// DEPTH-3 software pipeline: loads for batch b+2 issued while batch b
// computes -> ~2 batch-computes (~600cy) of latency tolerance per gather,
// and (2 in flight) x (4 waves/SIMD) = 8 outstanding gather batches per
// SIMD vs 5 before. All pipeline indices are compile-time (full unroll),
// so the [3] arrays stay in registers. ----
__global__ __launch_bounds__(256) void k_ev(
    const ushort_t* __restrict__ xlb, const ushort_t* __restrict__ xrb,
    const ushort_t* __restrict__ ea, const int* __restrict__ srcs,
    const int* __restrict__ pdst, const float* __restrict__ WeL,
    const float* __restrict__ attL, float* __restrict__ evf) {
    int wid = blockIdx.x * 4 + (threadIdx.x >> 6);
    int lane = threadIdx.x & 63;
    if (wid >= N_EDGES / 128) return;
    int col = lane & 15, quad = lane >> 4;
    int comp = col & 1, base = col >> 1;

    // preload this wave's 128 srcs/pdst values (2 per lane)
    int2 sp = *(const int2*)(srcs + wid * 128 + 2 * lane);
    int2 dp = *(const int2*)(pdst + wid * 128 + 2 * lane);

    // wave-invariant A fragments (We^T, remapped channels)
    bf16x8 afr[6];
#pragma unroll
    for (int mc = 0; mc < 6; mc++) {
        bf16x8 a = {0, 0, 0, 0, 0, 0, 0, 0};
        if (quad < 2) {
            int ch = (col >> 2) * 24 + mc * 4 + (col & 3);
#pragma unroll
            for (int j = 0; j < 8; j++)
                a[j] = (short)f2bf(WeL[(quad * 8 + j) * HID + ch]);
        }
        afr[mc] = a;
    }
    // att for this lane's head (= quad)
    float attr[6][4];
#pragma unroll
    for (int mc = 0; mc < 6; mc++)
#pragma unroll
        for (int r = 0; r < 4; r++)
            attr[mc][r] = attL[quad * 24 + mc * 4 + r];

    // pipeline registers (3 batches in flight)
    bf16x8 bfr[3];
    uint4 xq[3][3], rq[3][3];

    auto getsd = [&](int b, int& sv, int& dv) {
        int sl = b * 8 + base;
        int sx = __shfl(sp.x, sl), sy = __shfl(sp.y, sl);
        int dx = __shfl(dp.x, sl), dy = __shfl(dp.y, sl);
        sv = comp ? sy : sx;
        dv = comp ? dy : dx;
    };
    auto issue = [&](int b, int pp) {
        int sv, dv;
        getsd(b, sv, dv);
        int p = wid * 128 + b * 16 + col;
        bf16x8 z8 = {0, 0, 0, 0, 0, 0, 0, 0};
        bfr[pp] = (quad < 2) ? *(const bf16x8*)(ea + (size_t)p * ED + quad * 8) : z8;
        const uint4* xp = (const uint4*)(xlb + (size_t)sv * HID + quad * 24);
        const uint4* rp = (const uint4*)(xrb + (size_t)dv * HID + quad * 24);
#pragma unroll
        for (int i = 0; i < 3; i++) {
            xq[pp][i] = xp[i];
            rq[pp][i] = rp[i];
        }
    };

    issue(0, 0);
    issue(1, 1);
#pragma unroll
    for (int b = 0; b < 8; b++) {
        int pp = b % 3;
        if (b < 6) issue(b + 2, (b + 2) % 3);

        f32x4 zero4 = {0.f, 0.f, 0.f, 0.f};
        f32x4 d[6];
#pragma unroll
        for (int mc = 0; mc < 6; mc++)
            d[mc] = __builtin_amdgcn_mfma_f32_16x16x32_bf16(afr[mc], bfr[pp], zero4, 0, 0, 0);

        uint_t ux[12] = {xq[pp][0].x, xq[pp][0].y, xq[pp][0].z, xq[pp][0].w,
                         xq[pp][1].x, xq[pp][1].y, xq[pp][1].z, xq[pp][1].w,
                         xq[pp][2].x, xq[pp][2].y, xq[pp][2].z, xq[pp][2].w};
        uint_t ur[12] = {rq[pp][0].x, rq[pp][0].y, rq[pp][0].z, rq[pp][0].w,
                         rq[pp][1].x, rq[pp][1].y, rq[pp][1].z, rq[pp][1].w,
                         rq[pp][2].x, rq[pp][2].y, rq[pp][2].z, rq[pp][2].w};
        float logit = 0.f;
#pragma unroll
        for (int mc = 0; mc < 6; mc++) {
            uint_t aL = ux[2 * mc], aH = ux[2 * mc + 1];
            uint_t rL = ur[2 * mc], rH = ur[2 * mc + 1];
            float x0 = bf2f((ushort_t)(aL & 0xffff)), x1 = bf2f((ushort_t)(aL >> 16));
            float x2 = bf2f((ushort_t)(aH & 0xffff)), x3 = bf2f((ushort_t)(aH >> 16));
            float r0 = bf2f((ushort_t)(rL & 0xffff)), r1 = bf2f((ushort_t)(rL >> 16));
            float r2 = bf2f((ushort_t)(rH & 0xffff)), r3 = bf2f((ushort_t)(rH >> 16));
            float z0 = x0 + r0 + d[mc][0]; z0 = z0 > 0.f ? z0 : 0.2f * z0;
            float z1 = x1 + r1 + d[mc][1]; z1 = z1 > 0.f ? z1 : 0.2f * z1;
            float z2 = x2 + r2 + d[mc][2]; z2 = z2 > 0.f ? z2 : 0.2f * z2;
            float z3 = x3 + r3 + d[mc][3]; z3 = z3 > 0.f ? z3 : 0.2f * z3;
            logit += z0 * attr[mc][0] + z1 * attr[mc][1] +
                     z2 * attr[mc][2] + z3 * attr[mc][3];
        }
        int p = wid * 128 + b * 16 + col;
        evf[4 * p + quad] = __expf(logit);   // coalesced: 64 lanes, 256B run
    }
}

// ---- k_agg: weighted sum + residual + LayerNorm. 8 edge-slots x 8 lanes
// (12 ch/lane, 3x8B loads), serial gather depth = deg/8, 2-stage pipeline. ----
__global__ __launch_bounds__(256) void k_agg(
    const ushort_t* __restrict__ xlb, const float* __restrict__ evf,
    const int* __restrict__ srcs, const int* __restrict__ rowptr,
    const float* __restrict__ convb, const float* __restrict__ lng,
    const float* __restrict__ lnb, float* __restrict__ h) {
    int lane = threadIdx.x & 63;
    int node = blockIdx.x * 4 + (threadIdx.x >> 6);
    int slot = lane >> 3, q = lane & 7;      // 8 slots x 8 channel-lanes
    int c0 = q * 12, head = q >> 1;          // 12 ch/lane; head = c0/24
    int beg = rowptr[node], end = rowptr[node + 1];
    int cnt = (end - beg + 7) >> 3;

    float n[12];
#pragma unroll
    for (int j = 0; j < 12; j++) n[j] = 0.f;
    float den = 0.f;

    if (cnt > 0) {
        int p = beg + slot;
        bool v = p < end;
        int pc = v ? p : beg;
        int src = srcs[pc];
        float evv = evf[4 * pc + head];
        const ushort_t* xp = xlb + (size_t)src * HID + c0;
        uint2 A0 = *(const uint2*)(xp);
        uint2 A1 = *(const uint2*)(xp + 4);
        uint2 A2 = *(const uint2*)(xp + 8);
        for (int it = 0; it < cnt; ++it) {
            int pn = beg + (it + 1) * 8 + slot;
            bool vn = pn < end;
            int pcn = vn ? pn : beg;
            int srcn = srcs[pcn];
            float evn = evf[4 * pcn + head];
            const ushort_t* xpn = xlb + (size_t)srcn * HID + c0;
            uint2 B0 = *(const uint2*)(xpn);
            uint2 B1 = *(const uint2*)(xpn + 4);
            uint2 B2 = *(const uint2*)(xpn + 8);

            float e = v ? evv : 0.f;
            n[0]  += e * bf2f((ushort_t)(A0.x & 0xffff));
            n[1]  += e * bf2f((ushort_t)(A0.x >> 16));
            n[2]  += e * bf2f((ushort_t)(A0.y & 0xffff));
            n[3]  += e * bf2f((ushort_t)(A0.y >> 16));
            n[4]  += e * bf2f((ushort_t)(A1.x & 0xffff));
            n[5]  += e * bf2f((ushort_t)(A1.x >> 16));
            n[6]  += e * bf2f((ushort_t)(A1.y & 0xffff));
            n[7]  += e * bf2f((ushort_t)(A1.y >> 16));
            n[8]  += e * bf2f((ushort_t)(A2.x & 0xffff));
            n[9]  += e * bf2f((ushort_t)(A2.x >> 16));
            n[10] += e * bf2f((ushort_t)(A2.y & 0xffff));
            n[11] += e * bf2f((ushort_t)(A2.y >> 16));
            den += e;

            v = vn; evv = evn;
            A0 = B0; A1 = B1; A2 = B2;
        }
    }
    // combine 8 slots
#pragma unroll
    for (int j = 0; j < 12; j++) {
        n[j] += __shfl_xor(n[j], 8);
        n[j] += __shfl_xor(n[j], 16);
        n[j] += __shfl_xor(n[j], 32);
    }
    den += __shfl_xor(den, 8);
    den += __shfl_xor(den, 16);
    den += __shfl_xor(den, 32);

    size_t nb = (size_t)node * HID + c0;
    float inv = 1.f / (den + 1e-16f);
    float4 h0 = *(const float4*)(h + nb);
    float4 h1 = *(const float4*)(h + nb + 4);
    float4 h2 = *(const float4*)(h + nb + 8);
    float vv[12] = {h0.x, h0.y, h0.z, h0.w, h1.x, h1.y, h1.z, h1.w,
                    h2.x, h2.y, h2.z, h2.w};
    float sm = 0.f;
#pragma unroll
    for (int j = 0; j < 12; j++) {
        vv[j] += n[j] * inv + convb[c0 + j];
        sm += vv[j];
    }
    sm += __shfl_xor(sm, 1); sm += __shfl_xor(sm, 2); sm += __shfl_xor(sm, 4);
    float mu = sm * (1.f / 96.f);
    float sv = 0.f;
#pragma unroll
    for (int j = 0; j < 12; j++) {
        vv[j] -= mu;
        sv += vv[j] * vv[j];
    }
    sv += __shfl_xor(sv, 1); sv += __shfl_xor(sv, 2); sv += __shfl_xor(sv, 4);
    float rstd = rsqrtf(sv * (1.f / 96.f) + 1e-5f);
    if (slot == 0) {
        float o[12];
#pragma unroll
        for (int j = 0; j < 12; j++)
            o[j] = vv[j] * rstd * lng[c0 + j] + lnb[c0 + j];
        *(float4*)(h + nb)     = make_float4(o[0], o[1], o[2], o[3]);
        *(float4*)(h + nb + 4) = make_float4(o[4], o[5], o[6], o[7]);
        *(float4*)(h + nb + 8) = make_float4(o[8], o[9], o[10], o[11]);
    }
}

// ---- k_head_mfma: out = gelu(h@W1+b1)@W2+b2 via MFMA ----
__global__ __launch_bounds__(256) void k_head_mfma(
    const float* __restrict__ h, const float* __restrict__ W1,
    const float* __restrict__ b1, const float* __restrict__ W2,
    const float* __restrict__ b2, float* __restrict__ out) {
    __shared__ ushort_t sW[48 * 104];
    __shared__ float sB1[48];
    __shared__ float sW2[48];
    int t = threadIdx.x;
    for (int idx = t; idx < 48 * 96; idx += 256) {
        int j = idx % 48, k = idx / 48;
        sW[j * 104 + k] = f2bf(W1[k * 48 + j]);
    }
    if (t < 48) { sB1[t] = b1[t]; sW2[t] = W2[t]; }
    __syncthreads();

    int wv = t >> 6, lane = t & 63;
    int m0 = blockIdx.x * 64 + wv * 16;
    if (m0 >= N_NODES) return;
    int col = lane & 15, quad = lane >> 4;

    bf16x8 afr[3];
    const float* hrow = h + (size_t)(m0 + col) * HID;
#pragma unroll
    for (int s = 0; s < 3; s++) {
        float4 v0 = *(const float4*)(hrow + s * 32 + quad * 8);
        float4 v1 = *(const float4*)(hrow + s * 32 + quad * 8 + 4);
        bf16x8 a;
        a[0] = (short)f2bf(v0.x); a[1] = (short)f2bf(v0.y);
        a[2] = (short)f2bf(v0.z); a[3] = (short)f2bf(v0.w);
        a[4] = (short)f2bf(v1.x); a[5] = (short)f2bf(v1.y);
        a[6] = (short)f2bf(v1.z); a[7] = (short)f2bf(v1.w);
        afr[s] = a;
    }

    const float inv_sqrt2 = 0.70710678118654752f;
    float y0 = 0.f, y1 = 0.f, y2 = 0.f, y3 = 0.f;
#pragma unroll
    for (int nt = 0; nt < 3; nt++) {
        f32x4 acc = {0.f, 0.f, 0.f, 0.f};
#pragma unroll
        for (int s = 0; s < 3; s++) {
            bf16x8 bfr = *(const bf16x8*)(sW + (nt * 16 + col) * 104 + s * 32 + quad * 8);
            acc = __builtin_amdgcn_mfma_f32_16x16x32_bf16(afr[s], bfr, acc, 0, 0, 0);
        }
        int ch = nt * 16 + col;
        float bias = sB1[ch], w2 = sW2[ch];
        float v, g;
        v = acc[0] + bias; g = 0.5f * v * (1.f + erff(v * inv_sqrt2)); y0 += g * w2;
        v = acc[1] + bias; g = 0.5f * v * (1.f + erff(v * inv_sqrt2)); y1 += g * w2;
        v = acc[2] + bias; g = 0.5f * v * (1.f + erff(v * inv_sqrt2)); y2 += g * w2;
        v = acc[3] + bias; g = 0.5f * v * (1.f + erff(v * inv_sqrt2)); y3 += g * w2;
    }
    y0 += __shfl_xor(y0, 1); y0 += __shfl_xor(y0, 2);
    y0 += __shfl_xor(y0, 4); y0 += __shfl_xor(y0, 8);
    y1 += __shfl_xor(y1, 1); y1 += __shfl_xor(y1, 2);
    y1 += __shfl_xor(y1, 4); y1 += __shfl_xor(y1, 8);
    y2 += __shfl_xor(y2, 1); y2 += __shfl_xor(y2, 2);
    y2 += __shfl_xor(y2, 4); y2 += __shfl_xor(y2, 8);
    y3 += __shfl_xor(y3, 1); y3 += __shfl_xor(y3, 2);
    y3 += __shfl_xor(y3, 4); y3 += __shfl_xor(y3, 8);
    if (col == 0) {
        float bb = b2[0];
        out[m0 + quad * 4 + 0] = y0 + bb;
        out[m0 + quad * 4 + 1] = y1 + bb;
        out[m0 + quad * 4 + 2] = y2 + bb;
        out[m0 + quad * 4 + 3] = y3 + bb;
    }
}

extern "C" void kernel_launch(void* const* d_in, const int* in_sizes, int n_in,
                              void* d_out, int out_size, void* d_ws, size_t ws_size,
                              hipStream_t stream) {
    const float* x       = (const float*)d_in[0];
    const int*   eidx    = (const int*)  d_in[1];
    const float* eattr   = (const float*)d_in[2];
    const float* proj_w  = (const float*)d_in[3];
    const float* proj_b  = (const float*)d_in[4];
    const float* lin_l_w = (const float*)d_in[5];
    const float* lin_l_b = (const float*)d_in[6];
    const float* lin_r_w = (const float*)d_in[7];
    const float* lin_r_b = (const float*)d_in[8];
    const float* lin_e_w = (const float*)d_in[9];
    const float* att     = (const float*)d_in[10];
    const float* conv_b  = (const float*)d_in[11];
    const float* ln_g    = (const float*)d_in[12];
    const float* ln_b    = (const float*)d_in[13];
    const float* head_w1 = (const float*)d_in[14];
    const float* head_b1 = (const float*)d_in[15];
    const float* head_w2 = (const float*)d_in[16];
    const float* head_b2 = (const float*)d_in[17];
    float* out = (float*)d_out;

    char* p = (char*)d_ws;
    auto alloc = [&](size_t bytes) -> char* {
        char* r = p;
        p += (bytes + 255) & ~size_t(255);
        return r;
    };
    float*    h      = (float*)alloc(sizeof(float) * (size_t)N_NODES * HID);
    ushort_t* xl     = (ushort_t*)alloc(2 * (size_t)N_NODES * HID);
    ushort_t* xr     = (ushort_t*)alloc(2 * (size_t)N_NODES * HID);
    int*      cnt    = (int*)alloc(4 * (size_t)N_NODES);
    int*      rank   = (int*)alloc(4 * (size_t)N_EDGES);
    int*      rowptr = (int*)alloc(4 * (size_t)(N_NODES + 1));
    int*      bsum   = (int*)alloc(4 * 256);
    int2*     csre   = (int2*)alloc(8 * (size_t)N_EDGES);
    int*      srcs   = (int*)alloc(4 * ((size_t)N_EDGES + 256));
    int*      pdst   = (int*)alloc(4 * ((size_t)N_EDGES + 256));
    ushort_t* ea_csr = (ushort_t*)alloc(2 * (size_t)N_EDGES * ED);
    float*    ev     = (float*)alloc(16 * (size_t)N_EDGES);

    const int* srcA = eidx;
    const int* dstA = eidx + N_EDGES;

    int ebl = (N_EDGES + 255) / 256;   // 3125
    int nbl = (N_NODES + 255) / 256;   // 196

    hipMemsetAsync(cnt, 0, 4 * (size_t)N_NODES, stream);
    k_rank<<<ebl, 256, 0, stream>>>(dstA, cnt, rank);
    k_scan_block<<<nbl, 256, 0, stream>>>(cnt, rowptr, bsum);
    k_scan_bsum<<<1, 256, 0, stream>>>(bsum, nbl);
    k_scan_add<<<nbl, 256, 0, stream>>>(rowptr, bsum);
    k_place<<<ebl, 256, 0, stream>>>(srcA, dstA, rank, rowptr, csre);
    k_gather<<<ebl, 256, 0, stream>>>(csre, dstA, eattr, srcs, pdst, ea_csr);

    k_proj<<<N_NODES / 16, 192, 0, stream>>>(x, proj_w, proj_b, h);
    for (int l = 0; l < NLAYER; l++) {
        k_linlr_mfma<<<(N_NODES + 63) / 64, 256, 0, stream>>>(
            h, lin_l_w + (size_t)l * HID * HID, lin_l_b + (size_t)l * HID,
            lin_r_w + (size_t)l * HID * HID, lin_r_b + (size_t)l * HID, xl, xr);
        k_ev<<<1563, 256, 0, stream>>>(xl, xr, ea_csr, srcs, pdst,
                                       lin_e_w + (size_t)l * ED * HID,
                                       att + (size_t)l * HID, ev);
        k_agg<<<N_NODES / 4, 256, 0, stream>>>(
            xl, ev, srcs, rowptr, conv_b + (size_t)l * HID,
            ln_g + (size_t)l * HID, ln_b + (size_t)l * HID, h);
    }
    k_head_mfma<<<(N_NODES + 63) / 64, 256, 0, stream>>>(h, head_w1, head_b1,
                                                         head_w2, head_b2, out);
}